// Round 4
// baseline (363.923 us; speedup 1.0000x reference)
//
#include <hip/hip_runtime.h>

#define E_EDGES 800000
#define NN 50000
#define OUT_STRIDE 288

typedef __bf16 bf16;
typedef bf16 bf16x8 __attribute__((ext_vector_type(8)));
typedef float floatx4 __attribute__((ext_vector_type(4)));
typedef float floatx2 __attribute__((ext_vector_type(2)));
typedef unsigned short ushort8v __attribute__((ext_vector_type(8)));

__device__ __forceinline__ unsigned short f2bf(float f){
    return __builtin_bit_cast(unsigned short, (bf16)f);
}
__device__ __forceinline__ unsigned pack2bf(float a, float b){
    unsigned short lo = __builtin_bit_cast(unsigned short, (bf16)a);
    unsigned short hi = __builtin_bit_cast(unsigned short, (bf16)b);
    return (unsigned)lo | ((unsigned)hi << 16);
}
__device__ __forceinline__ float bf2f(unsigned short h){
    return __uint_as_float((unsigned)h << 16);
}
// monotone float<->uint for atomicMax/Min
__device__ __forceinline__ unsigned encf(float f){
    unsigned u = __float_as_uint(f);
    return (u & 0x80000000u) ? ~u : (u | 0x80000000u);
}
__device__ __forceinline__ float decf(unsigned u){
    return __uint_as_float((u & 0x80000000u) ? (u ^ 0x80000000u) : ~u);
}
__device__ __forceinline__ floatx4 mfma16(ushort8v a, ushort8v b, floatx4 c){
    return __builtin_amdgcn_mfma_f32_16x16x32_bf16(
        __builtin_bit_cast(bf16x8, a), __builtin_bit_cast(bf16x8, b), c, 0, 0, 0);
}
__device__ __forceinline__ void flush_run(float* out, int node, float s, float mx, float mn, int lane){
    float* sp = out + (long)node * OUT_STRIDE + 64;
    atomicAdd(sp + lane, s);
    atomicMax((unsigned*)sp + 64 + lane, encf(mx));
    atomicMin((unsigned*)sp + 128 + lane, encf(mn));
}
// h1 = relu(P(bf16) + Q(fp8)) -> bf16 B-frag
__device__ __forceinline__ ushort8v combine_relu_pq(ushort8v p, uint2 q){
    floatx2 q01 = __builtin_amdgcn_cvt_pk_f32_fp8((int)q.x, false);
    floatx2 q23 = __builtin_amdgcn_cvt_pk_f32_fp8((int)q.x, true);
    floatx2 q45 = __builtin_amdgcn_cvt_pk_f32_fp8((int)q.y, false);
    floatx2 q67 = __builtin_amdgcn_cvt_pk_f32_fp8((int)q.y, true);
    uint4 o;
    o.x = pack2bf(fmaxf(bf2f(p[0]) + q01[0], 0.f), fmaxf(bf2f(p[1]) + q01[1], 0.f));
    o.y = pack2bf(fmaxf(bf2f(p[2]) + q23[0], 0.f), fmaxf(bf2f(p[3]) + q23[1], 0.f));
    o.z = pack2bf(fmaxf(bf2f(p[4]) + q45[0], 0.f), fmaxf(bf2f(p[5]) + q45[1], 0.f));
    o.w = pack2bf(fmaxf(bf2f(p[6]) + q67[0], 0.f), fmaxf(bf2f(p[7]) + q67[1], 0.f));
    return __builtin_bit_cast(ushort8v, o);
}

// ---------------- setup: init out accum | prepack weights | hist ----------------
#define INIT_N 2400000
#define PK_N   40960
#define SETUP_TOTAL (INIT_N + PK_N + E_EDGES)

__global__ void setup_kernel(const int* __restrict__ ei,
                             const float* __restrict__ W1, const float* __restrict__ W2,
                             const float* __restrict__ W3,
                             unsigned short* __restrict__ wp,
                             int* __restrict__ cnt, float* __restrict__ out)
{
    int i = blockIdx.x * blockDim.x + threadIdx.x;
    if (i < INIT_N) {
        // out row: [P 0..16 | sum 16..32 | max 32..48 | min 48..64 | u 64..72] uint4 units
        int row = i / 48, q = i % 48;
        uint4 val = (q < 32) ? make_uint4(0u, 0u, 0u, 0u)
                             : make_uint4(~0u, ~0u, ~0u, ~0u);
        ((uint4*)out)[(long)row * 72 + 16 + q] = val;
        return;
    }
    i -= INIT_N;
    if (i < PK_N) {
        // A-fragment pack (weights as A): wp[f*8+j] = W[kc*32+quad*8+j][nt*16+ln]
        const float* W; int N; int idx;
        if (i < 16384)      { W = W1; N = 128; idx = i; }
        else if (i < 32768) { W = W2; N = 128; idx = i - 16384; }
        else                { W = W3; N = 64;  idx = i - 32768; }
        int j = idx & 7, lane = (idx >> 3) & 63, kc = (idx >> 9) & 3, nt = idx >> 11;
        wp[i] = f2bf(W[(kc * 32 + ((lane >> 4) & 3) * 8 + j) * N + nt * 16 + (lane & 15)]);
        return;
    }
    i -= PK_N;
    if (i < E_EDGES) atomicAdd(&cnt[ei[E_EDGES + i]], 1);
}

// ---------------- per-node P/Q precompute ----------------
// P[n] = x[n]*W1a + b1 (bf16, 128ch) -> out[n] bytes 0..255 (exact fit, sum starts at 256)
// Q[n] = x[n]*W1b      (fp8 e4m3, 128ch) -> qb + n*128
#define PQ_BLOCKS 391
__global__ __launch_bounds__(256, 4) void pq_kernel(
    const float* __restrict__ x, const unsigned short* __restrict__ wp,
    const float* __restrict__ b1, float* __restrict__ out, unsigned char* __restrict__ qb)
{
    const int tid = threadIdx.x, lane = tid & 63, w = tid >> 6;
    const int quad = lane >> 4, ln = lane & 15;
    const ushort8v* wpv = (const ushort8v*)wp;
    const int nbase = (blockIdx.x * 4 + w) * 32;
    const int n0 = nbase + ln, n1 = nbase + 16 + ln;
    const int n0c = min(n0, NN - 1), n1c = min(n1, NN - 1);

    ushort8v X0[2], X1[2];
#pragma unroll
    for (int c = 0; c < 2; c++){
        const float4* p0 = (const float4*)(x + (long)n0c * 64 + c * 32 + quad * 8);
        const float4* p1 = (const float4*)(x + (long)n1c * 64 + c * 32 + quad * 8);
        float4 a = p0[0], b = p0[1];
        float4 cc = p1[0], d = p1[1];
        uint4 u0, u1;
        u0.x = pack2bf(a.x, a.y);  u0.y = pack2bf(a.z, a.w);
        u0.z = pack2bf(b.x, b.y);  u0.w = pack2bf(b.z, b.w);
        u1.x = pack2bf(cc.x, cc.y); u1.y = pack2bf(cc.z, cc.w);
        u1.z = pack2bf(d.x, d.y);  u1.w = pack2bf(d.z, d.w);
        X0[c] = __builtin_bit_cast(ushort8v, u0);
        X1[c] = __builtin_bit_cast(ushort8v, u1);
    }
    unsigned char* ob = (unsigned char*)out;
#pragma unroll
    for (int nt = 0; nt < 8; nt++){
        floatx4 bini = *(const floatx4*)(b1 + nt * 16 + quad * 4);
        floatx4 z = {0.f, 0.f, 0.f, 0.f};
        floatx4 aP0 = bini, aP1 = bini, aQ0 = z, aQ1 = z;
        ushort8v Af0 = wpv[(nt * 4 + 0) * 64 + lane];
        ushort8v Af1 = wpv[(nt * 4 + 1) * 64 + lane];
        ushort8v Af2 = wpv[(nt * 4 + 2) * 64 + lane];
        ushort8v Af3 = wpv[(nt * 4 + 3) * 64 + lane];
        aP0 = mfma16(Af0, X0[0], aP0); aP0 = mfma16(Af1, X0[1], aP0);
        aP1 = mfma16(Af0, X1[0], aP1); aP1 = mfma16(Af1, X1[1], aP1);
        aQ0 = mfma16(Af2, X0[0], aQ0); aQ0 = mfma16(Af3, X0[1], aQ0);
        aQ1 = mfma16(Af2, X1[0], aQ1); aQ1 = mfma16(Af3, X1[1], aQ1);
        // P -> bf16 in out[0:256B of row]; channel c at byte 2c
        uint2 sP0, sP1;
        sP0.x = pack2bf(aP0[0], aP0[1]); sP0.y = pack2bf(aP0[2], aP0[3]);
        sP1.x = pack2bf(aP1[0], aP1[1]); sP1.y = pack2bf(aP1[2], aP1[3]);
        int bo = nt * 32 + quad * 8;  // byte offset of channel nt*16+quad*4
        // Q -> fp8; channel c at byte c
        int q0p = __builtin_amdgcn_cvt_pk_fp8_f32(aQ0[0], aQ0[1], 0, false);
        q0p     = __builtin_amdgcn_cvt_pk_fp8_f32(aQ0[2], aQ0[3], q0p, true);
        int q1p = __builtin_amdgcn_cvt_pk_fp8_f32(aQ1[0], aQ1[1], 0, false);
        q1p     = __builtin_amdgcn_cvt_pk_fp8_f32(aQ1[2], aQ1[3], q1p, true);
        int qo = nt * 16 + quad * 4;
        if (n0 < NN){
            *(uint2*)(ob + (long)n0 * 1152 + bo) = sP0;
            *(int*)(qb + (long)n0 * 128 + qo)    = q0p;
        }
        if (n1 < NN){
            *(uint2*)(ob + (long)n1 * 1152 + bo) = sP1;
            *(int*)(qb + (long)n1 * 128 + qo)    = q1p;
        }
    }
}

// ---------------- counting sort by destination ----------------
__global__ void scanA_kernel(const int* __restrict__ cnt, int* __restrict__ off,
                             int* __restrict__ bsum){
    __shared__ int s[256];
    int tid = threadIdx.x;
    int node = blockIdx.x * 196 + tid;
    int val = (tid < 196 && node < NN) ? cnt[node] : 0;
    s[tid] = val;
    __syncthreads();
    for (int d = 1; d < 256; d <<= 1){
        int t = (tid >= d) ? s[tid - d] : 0;
        __syncthreads();
        s[tid] += t;
        __syncthreads();
    }
    if (tid < 196 && node < NN) off[node] = s[tid] - val;  // local exclusive
    if (tid == 255) bsum[blockIdx.x] = s[255];             // block total
}

__global__ void scanB_kernel(const int* __restrict__ bsum, int* __restrict__ bbase){
    __shared__ int s[256];
    int tid = threadIdx.x;
    int val = bsum[tid];
    s[tid] = val;
    __syncthreads();
    for (int d = 1; d < 256; d <<= 1){
        int t = (tid >= d) ? s[tid - d] : 0;
        __syncthreads();
        s[tid] += t;
        __syncthreads();
    }
    bbase[tid] = s[tid] - val;  // exclusive
}

// scatter (+ fused scanC): global pos = local excl + block base
__global__ void scatter_kernel(const int* __restrict__ ei, int* __restrict__ off,
                               const int* __restrict__ bbase, int2* __restrict__ enodes){
    int e = blockIdx.x * blockDim.x + threadIdx.x;
    if (e >= E_EDGES) return;
    int c = ei[E_EDGES + e], r = ei[e];
    int pos = atomicAdd(&off[c], 1) + bbase[c / 196];
    enodes[pos] = make_int2(r, c);
}

// ---------------- edge MLP: 32 edges per wave-tile, barrier-free ----------------
// Layer 1 replaced by gather of precomputed P[row] (bf16, in out rows) and
// Q[col] (fp8, in qb) + f32 add + relu, landing directly in B-fragment layout.
// Remaining transposes run in two half-passes over a 4608 B/wave buffer.
__global__ __launch_bounds__(256, 5) void edge_mlp_kernel(
    const int2* __restrict__ enodes, const unsigned short* __restrict__ wp,
    const unsigned char* __restrict__ qb,
    const float* __restrict__ b2, const float* __restrict__ b3,
    float* __restrict__ out)
{
    __shared__ __align__(16) unsigned char smem[4 * 4608];

    const int tid  = threadIdx.x;
    const int lane = tid & 63;
    const int w    = tid >> 6;
    const int quad = lane >> 4;
    const int ln   = lane & 15;
    unsigned short* wbuf = (unsigned short*)(smem + w * 4608);  // 32 rows x 72 u16
    float* Tf = (float*)wbuf;                                    // 32 rows x 36 f32
    const ushort8v* wpv = (const ushort8v*)wp;

    const int g = blockIdx.x * 4 + w;       // tile id, 25000 total
    const int ebase = g * 32;
    int2 ed0 = enodes[ebase + ln];
    int2 ed1 = enodes[ebase + 16 + ln];
    const int cn0 = ed0.y, cn1 = ed1.y;

    // ---- "layer 1": gather P[row] + Q[col] -> h1 B-frags ----
    const unsigned short* pqb = (const unsigned short*)out;  // P in out rows, bytes 0..255
    ushort8v H0[4], H1[4];
#pragma unroll
    for (int kc = 0; kc < 4; kc++){
        const int o = kc * 32 + quad * 8;   // u16 index == fp8 byte index
        ushort8v p0 = *(const ushort8v*)(pqb + (long)ed0.x * 576 + o);
        ushort8v p1 = *(const ushort8v*)(pqb + (long)ed1.x * 576 + o);
        uint2 q0 = *(const uint2*)(qb + (long)ed0.y * 128 + o);
        uint2 q1 = *(const uint2*)(qb + (long)ed1.y * 128 + o);
        H0[kc] = combine_relu_pq(p0, q0);
        H1[kc] = combine_relu_pq(p1, q1);
    }

    // ---- layer 2 (sets 8..15), two half-passes of 64 och each ----
    ushort8v G0[4], G1[4];
#pragma unroll
    for (int hv = 0; hv < 2; hv++){
#pragma unroll
        for (int q2 = 0; q2 < 4; q2++){
            int nt = hv * 4 + q2;
            floatx4 bini = *(const floatx4*)(b2 + nt * 16 + quad * 4);
            floatx4 a0 = bini, a1 = bini;
#pragma unroll
            for (int kc = 0; kc < 4; kc++){
                ushort8v Af = wpv[2048 + (nt * 4 + kc) * 64 + lane];
                a0 = mfma16(Af, H0[kc], a0);
                a1 = mfma16(Af, H1[kc], a1);
            }
            uint2 p0, p1;
            p0.x = pack2bf(fmaxf(a0[0], 0.f), fmaxf(a0[1], 0.f));
            p0.y = pack2bf(fmaxf(a0[2], 0.f), fmaxf(a0[3], 0.f));
            p1.x = pack2bf(fmaxf(a1[0], 0.f), fmaxf(a1[1], 0.f));
            p1.y = pack2bf(fmaxf(a1[2], 0.f), fmaxf(a1[3], 0.f));
            int col = q2 * 16 + quad * 4;
            *(uint2*)(wbuf + ln * 72 + col)        = p0;
            *(uint2*)(wbuf + (16 + ln) * 72 + col) = p1;
        }
#pragma unroll
        for (int c = 0; c < 2; c++){
            G0[hv * 2 + c] = *(const ushort8v*)(wbuf + ln * 72 + c * 32 + quad * 8);
            G1[hv * 2 + c] = *(const ushort8v*)(wbuf + (16 + ln) * 72 + c * 32 + quad * 8);
        }
    }

    // ---- layer 3 (sets 16..19) + epilogue, two halves of 32 och each ----
#pragma unroll
    for (int hv = 0; hv < 2; hv++){
#pragma unroll
        for (int q3 = 0; q3 < 2; q3++){
            int nt = hv * 2 + q3;
            floatx4 bini = *(const floatx4*)(b3 + nt * 16 + quad * 4);
            floatx4 a0 = bini, a1 = bini;
#pragma unroll
            for (int kc = 0; kc < 4; kc++){
                ushort8v Af = wpv[4096 + (nt * 4 + kc) * 64 + lane];
                a0 = mfma16(Af, G0[kc], a0);
                a1 = mfma16(Af, G1[kc], a1);
            }
            int row = q3 * 16 + quad * 4;
#pragma unroll
            for (int r = 0; r < 4; r++){
                Tf[(row + r) * 36 + ln]      = a0[r];
                Tf[(row + r) * 36 + 16 + ln] = a1[r];
            }
        }
        // epilogue half: active lanes [hv*32, hv*32+32) own channel och = lane
        if ((lane >> 5) == hv){
            float v[32];
#pragma unroll
            for (int jj = 0; jj < 8; jj++){
                floatx4 t = *(const floatx4*)(Tf + (lane & 31) * 36 + jj * 4);
                v[jj * 4 + 0] = t[0]; v[jj * 4 + 1] = t[1];
                v[jj * 4 + 2] = t[2]; v[jj * 4 + 3] = t[3];
            }
            int cur = __builtin_amdgcn_readlane(cn0, 0);
            float s = v[0], mx = v[0], mn = v[0];
#pragma unroll
            for (int j = 1; j < 32; j++){
                int nj = (j < 16) ? __builtin_amdgcn_readlane(cn0, j)
                                  : __builtin_amdgcn_readlane(cn1, j - 16);
                if (nj != cur){
                    flush_run(out, cur, s, mx, mn, lane);
                    cur = nj; s = v[j]; mx = v[j]; mn = v[j];
                } else {
                    s += v[j]; mx = fmaxf(mx, v[j]); mn = fminf(mn, v[j]);
                }
            }
            flush_run(out, cur, s, mx, mn, lane);
        }
    }
}

// ---------------- finalize ----------------
__global__ void finalize_kernel(const float* __restrict__ x, const float* __restrict__ u,
                                const int* __restrict__ batch, const int* __restrict__ cnt,
                                float* __restrict__ out)
{
    long i = (long)blockIdx.x * blockDim.x + threadIdx.x;
    if (i >= (long)NN * 72) return;
    int ndx = (int)(i / 72);
    int q   = (int)(i % 72);
    float4 res;
    if (q < 16) {
        res = ((const float4*)(x + (long)ndx * 64))[q];
    } else if (q < 32) {
        float4 sv = ((const float4*)out)[i];
        int k = cnt[ndx];
        float inv = 1.f / (float)(k > 0 ? k : 1);
        res.x = sv.x * inv; res.y = sv.y * inv; res.z = sv.z * inv; res.w = sv.w * inv;
    } else if (q < 64) {
        uint4 e = ((const uint4*)out)[i];
        bool ne = cnt[ndx] > 0;
        res.x = ne ? decf(e.x) : 0.f; res.y = ne ? decf(e.y) : 0.f;
        res.z = ne ? decf(e.z) : 0.f; res.w = ne ? decf(e.w) : 0.f;
    } else {
        res = ((const float4*)(u + (long)batch[ndx] * 32))[q - 64];
    }
    ((float4*)out)[i] = res;
}

extern "C" void kernel_launch(void* const* d_in, const int* in_sizes, int n_in,
                              void* d_out, int out_size, void* d_ws, size_t ws_size,
                              hipStream_t stream)
{
    const float* x     = (const float*)d_in[0];
    const int*   ei    = (const int*)d_in[1];
    // d_in[2] = edge_attr (unused)
    const float* u     = (const float*)d_in[3];
    const int*   batch = (const int*)d_in[4];
    const float* W1    = (const float*)d_in[5];
    const float* b1    = (const float*)d_in[6];
    const float* W2    = (const float*)d_in[7];
    const float* b2    = (const float*)d_in[8];
    const float* W3    = (const float*)d_in[9];
    const float* b3    = (const float*)d_in[10];
    float* out = (float*)d_out;
    unsigned char* ws = (unsigned char*)d_ws;

    // ws layout (16B-aligned) — total 13,283,968 B (same footprint as round 1)
    unsigned short* wp     = (unsigned short*)ws;              //    81,920 B
    int*            cnt    = (int*)(ws + 81920);               //   200,000 B
    int*            off    = (int*)(ws + 281920);              //   200,000 B
    int*            bsum   = (int*)(ws + 481920);              //     1,024 B
    int*            bbase  = (int*)(ws + 482944);              //     1,024 B
    int2*           enodes = (int2*)(ws + 483968);             // 6,400,000 B
    unsigned char*  qb     = (unsigned char*)(ws + 6883968);   // 6,400,000 B (Q fp8)

    hipMemsetAsync(cnt, 0, 200000, stream);
    setup_kernel<<<(SETUP_TOTAL + 255) / 256, 256, 0, stream>>>(ei, W1, W2, W3, wp, cnt, out);
    pq_kernel<<<PQ_BLOCKS, 256, 0, stream>>>(x, wp, b1, out, qb);
    scanA_kernel<<<256, 256, 0, stream>>>(cnt, off, bsum);
    scanB_kernel<<<1, 256, 0, stream>>>(bsum, bbase);
    scatter_kernel<<<(E_EDGES + 255) / 256, 256, 0, stream>>>(ei, off, bbase, enodes);
    edge_mlp_kernel<<<6250, 256, 0, stream>>>(enodes, wp, qb, b2, b3, out);
    finalize_kernel<<<(int)(((long)NN * 72 + 255) / 256), 256, 0, stream>>>(x, u, batch, cnt, out);
}

// Round 5
// 343.093 us; speedup vs baseline: 1.0607x; 1.0607x over previous
//
#include <hip/hip_runtime.h>

#define E_EDGES 800000
#define NN 50000
#define OUT_STRIDE 288

typedef __bf16 bf16;
typedef bf16 bf16x8 __attribute__((ext_vector_type(8)));
typedef float floatx4 __attribute__((ext_vector_type(4)));
typedef float floatx2 __attribute__((ext_vector_type(2)));
typedef unsigned short ushort8v __attribute__((ext_vector_type(8)));

__device__ __forceinline__ unsigned short f2bf(float f){
    return __builtin_bit_cast(unsigned short, (bf16)f);
}
__device__ __forceinline__ unsigned pack2bf(float a, float b){
    unsigned short lo = __builtin_bit_cast(unsigned short, (bf16)a);
    unsigned short hi = __builtin_bit_cast(unsigned short, (bf16)b);
    return (unsigned)lo | ((unsigned)hi << 16);
}
// monotone float<->uint for atomicMax/Min
__device__ __forceinline__ unsigned encf(float f){
    unsigned u = __float_as_uint(f);
    return (u & 0x80000000u) ? ~u : (u | 0x80000000u);
}
__device__ __forceinline__ float decf(unsigned u){
    return __uint_as_float((u & 0x80000000u) ? (u ^ 0x80000000u) : ~u);
}
__device__ __forceinline__ floatx4 mfma16(ushort8v a, ushort8v b, floatx4 c){
    return __builtin_amdgcn_mfma_f32_16x16x32_bf16(
        __builtin_bit_cast(bf16x8, a), __builtin_bit_cast(bf16x8, b), c, 0, 0, 0);
}
__device__ __forceinline__ void flush_run(float* out, int node, float s, float mx, float mn, int lane){
    float* sp = out + (long)node * OUT_STRIDE + 64;
    atomicAdd(sp + lane, s);
    atomicMax((unsigned*)sp + 64 + lane, encf(mx));
    atomicMin((unsigned*)sp + 128 + lane, encf(mn));
}
// h1 = relu(P(fp8) + Q(fp8)) -> bf16 B-frag
__device__ __forceinline__ ushort8v combine_relu_fp8(uint2 p, uint2 q){
    floatx2 p01 = __builtin_amdgcn_cvt_pk_f32_fp8((int)p.x, false);
    floatx2 p23 = __builtin_amdgcn_cvt_pk_f32_fp8((int)p.x, true);
    floatx2 p45 = __builtin_amdgcn_cvt_pk_f32_fp8((int)p.y, false);
    floatx2 p67 = __builtin_amdgcn_cvt_pk_f32_fp8((int)p.y, true);
    floatx2 q01 = __builtin_amdgcn_cvt_pk_f32_fp8((int)q.x, false);
    floatx2 q23 = __builtin_amdgcn_cvt_pk_f32_fp8((int)q.x, true);
    floatx2 q45 = __builtin_amdgcn_cvt_pk_f32_fp8((int)q.y, false);
    floatx2 q67 = __builtin_amdgcn_cvt_pk_f32_fp8((int)q.y, true);
    floatx2 s01 = p01 + q01, s23 = p23 + q23, s45 = p45 + q45, s67 = p67 + q67;
    uint4 o;
    o.x = pack2bf(fmaxf(s01[0], 0.f), fmaxf(s01[1], 0.f));
    o.y = pack2bf(fmaxf(s23[0], 0.f), fmaxf(s23[1], 0.f));
    o.z = pack2bf(fmaxf(s45[0], 0.f), fmaxf(s45[1], 0.f));
    o.w = pack2bf(fmaxf(s67[0], 0.f), fmaxf(s67[1], 0.f));
    return __builtin_bit_cast(ushort8v, o);
}

// ---------------- setup: init out accum | (B: x->bf16) | prepack weights | hist ----------------
#define INIT_N 2400000
#define XBF_N  800000
#define PK_N   40960

template<int WITH_XBF>
__global__ void setup_kernel(const float* __restrict__ x, const int* __restrict__ ei,
                             const float* __restrict__ W1, const float* __restrict__ W2,
                             const float* __restrict__ W3,
                             unsigned short* __restrict__ wp, unsigned short* __restrict__ xbf,
                             int* __restrict__ cnt, float* __restrict__ out)
{
    int i = blockIdx.x * blockDim.x + threadIdx.x;
    if (i < INIT_N) {
        // out row: [x 0..16 | sum 16..32 | max 32..48 | min 48..64 | u 64..72] uint4 units
        int row = i / 48, q = i % 48;
        uint4 val = (q < 32) ? make_uint4(0u, 0u, 0u, 0u)
                             : make_uint4(~0u, ~0u, ~0u, ~0u);
        ((uint4*)out)[(long)row * 72 + 16 + q] = val;
        return;
    }
    i -= INIT_N;
    if constexpr (WITH_XBF) {
        if (i < XBF_N) {
            float4 v = ((const float4*)x)[i];
            ushort4 o; o.x = f2bf(v.x); o.y = f2bf(v.y); o.z = f2bf(v.z); o.w = f2bf(v.w);
            ((ushort4*)xbf)[i] = o;
            return;
        }
        i -= XBF_N;
    }
    if (i < PK_N) {
        // A-fragment pack (weights as A): wp[f*8+j] = W[kc*32+quad*8+j][nt*16+ln]
        const float* W; int N; int idx;
        if (i < 16384)      { W = W1; N = 128; idx = i; }
        else if (i < 32768) { W = W2; N = 128; idx = i - 16384; }
        else                { W = W3; N = 64;  idx = i - 32768; }
        int j = idx & 7, lane = (idx >> 3) & 63, kc = (idx >> 9) & 3, nt = idx >> 11;
        wp[i] = f2bf(W[(kc * 32 + ((lane >> 4) & 3) * 8 + j) * N + nt * 16 + (lane & 15)]);
        return;
    }
    i -= PK_N;
    if (i < E_EDGES) atomicAdd(&cnt[ei[E_EDGES + i]], 1);
}

// ---------------- per-node P/Q precompute (layout A only) ----------------
// P[n] = x[n]*W1a + b1, Q[n] = x[n]*W1b  -> fp8 e4m3, 128ch each, compact buffers
#define PQ_BLOCKS 391
__global__ __launch_bounds__(256, 4) void pq_kernel(
    const float* __restrict__ x, const unsigned short* __restrict__ wp,
    const float* __restrict__ b1,
    unsigned char* __restrict__ pb, unsigned char* __restrict__ qb)
{
    const int tid = threadIdx.x, lane = tid & 63, w = tid >> 6;
    const int quad = lane >> 4, ln = lane & 15;
    const ushort8v* wpv = (const ushort8v*)wp;
    const int nbase = (blockIdx.x * 4 + w) * 32;
    const int n0 = nbase + ln, n1 = nbase + 16 + ln;
    const int n0c = min(n0, NN - 1), n1c = min(n1, NN - 1);

    ushort8v X0[2], X1[2];
#pragma unroll
    for (int c = 0; c < 2; c++){
        const float4* p0 = (const float4*)(x + (long)n0c * 64 + c * 32 + quad * 8);
        const float4* p1 = (const float4*)(x + (long)n1c * 64 + c * 32 + quad * 8);
        float4 a = p0[0], b = p0[1];
        float4 cc = p1[0], d = p1[1];
        uint4 u0, u1;
        u0.x = pack2bf(a.x, a.y);  u0.y = pack2bf(a.z, a.w);
        u0.z = pack2bf(b.x, b.y);  u0.w = pack2bf(b.z, b.w);
        u1.x = pack2bf(cc.x, cc.y); u1.y = pack2bf(cc.z, cc.w);
        u1.z = pack2bf(d.x, d.y);  u1.w = pack2bf(d.z, d.w);
        X0[c] = __builtin_bit_cast(ushort8v, u0);
        X1[c] = __builtin_bit_cast(ushort8v, u1);
    }
#pragma unroll
    for (int nt = 0; nt < 8; nt++){
        floatx4 bini = *(const floatx4*)(b1 + nt * 16 + quad * 4);
        floatx4 z = {0.f, 0.f, 0.f, 0.f};
        floatx4 aP0 = bini, aP1 = bini, aQ0 = z, aQ1 = z;
        ushort8v Af0 = wpv[(nt * 4 + 0) * 64 + lane];
        ushort8v Af1 = wpv[(nt * 4 + 1) * 64 + lane];
        ushort8v Af2 = wpv[(nt * 4 + 2) * 64 + lane];
        ushort8v Af3 = wpv[(nt * 4 + 3) * 64 + lane];
        aP0 = mfma16(Af0, X0[0], aP0); aP0 = mfma16(Af1, X0[1], aP0);
        aP1 = mfma16(Af0, X1[0], aP1); aP1 = mfma16(Af1, X1[1], aP1);
        aQ0 = mfma16(Af2, X0[0], aQ0); aQ0 = mfma16(Af3, X0[1], aQ0);
        aQ1 = mfma16(Af2, X1[0], aQ1); aQ1 = mfma16(Af3, X1[1], aQ1);
        int p0p = __builtin_amdgcn_cvt_pk_fp8_f32(aP0[0], aP0[1], 0, false);
        p0p     = __builtin_amdgcn_cvt_pk_fp8_f32(aP0[2], aP0[3], p0p, true);
        int p1p = __builtin_amdgcn_cvt_pk_fp8_f32(aP1[0], aP1[1], 0, false);
        p1p     = __builtin_amdgcn_cvt_pk_fp8_f32(aP1[2], aP1[3], p1p, true);
        int q0p = __builtin_amdgcn_cvt_pk_fp8_f32(aQ0[0], aQ0[1], 0, false);
        q0p     = __builtin_amdgcn_cvt_pk_fp8_f32(aQ0[2], aQ0[3], q0p, true);
        int q1p = __builtin_amdgcn_cvt_pk_fp8_f32(aQ1[0], aQ1[1], 0, false);
        q1p     = __builtin_amdgcn_cvt_pk_fp8_f32(aQ1[2], aQ1[3], q1p, true);
        int qo = nt * 16 + quad * 4;
        if (n0 < NN){
            *(int*)(pb + (long)n0 * 128 + qo) = p0p;
            *(int*)(qb + (long)n0 * 128 + qo) = q0p;
        }
        if (n1 < NN){
            *(int*)(pb + (long)n1 * 128 + qo) = p1p;
            *(int*)(qb + (long)n1 * 128 + qo) = q1p;
        }
    }
}

// ---------------- counting sort by destination ----------------
__global__ void scanA_kernel(const int* __restrict__ cnt, int* __restrict__ off,
                             int* __restrict__ bsum){
    __shared__ int s[256];
    int tid = threadIdx.x;
    int node = blockIdx.x * 196 + tid;
    int val = (tid < 196 && node < NN) ? cnt[node] : 0;
    s[tid] = val;
    __syncthreads();
    for (int d = 1; d < 256; d <<= 1){
        int t = (tid >= d) ? s[tid - d] : 0;
        __syncthreads();
        s[tid] += t;
        __syncthreads();
    }
    if (tid < 196 && node < NN) off[node] = s[tid] - val;  // local exclusive
    if (tid == 255) bsum[blockIdx.x] = s[255];             // block total
}

__global__ void scanB_kernel(const int* __restrict__ bsum, int* __restrict__ bbase){
    __shared__ int s[256];
    int tid = threadIdx.x;
    int val = bsum[tid];
    s[tid] = val;
    __syncthreads();
    for (int d = 1; d < 256; d <<= 1){
        int t = (tid >= d) ? s[tid - d] : 0;
        __syncthreads();
        s[tid] += t;
        __syncthreads();
    }
    bbase[tid] = s[tid] - val;  // exclusive
}

// scatter variants (+ fused scanC)
__global__ void scatterA_kernel(const int* __restrict__ ei, int* __restrict__ off,
                                const int* __restrict__ bbase, unsigned* __restrict__ enodes){
    int e = blockIdx.x * blockDim.x + threadIdx.x;
    if (e >= E_EDGES) return;
    int c = ei[E_EDGES + e], r = ei[e];
    int pos = atomicAdd(&off[c], 1) + bbase[c / 196];
    enodes[pos] = (unsigned)r | ((unsigned)c << 16);   // both < 65536
}
__global__ void scatterB_kernel(const int* __restrict__ ei, int* __restrict__ off,
                                const int* __restrict__ bbase, int2* __restrict__ enodes){
    int e = blockIdx.x * blockDim.x + threadIdx.x;
    if (e >= E_EDGES) return;
    int c = ei[E_EDGES + e], r = ei[e];
    int pos = atomicAdd(&off[c], 1) + bbase[c / 196];
    enodes[pos] = make_int2(r, c);
}

// ---------------- edge MLP variant A: P/Q fp8 gather, 4.6KB LDS/wave, 8 blocks/CU ----------------
__global__ __launch_bounds__(256, 6) void edge_mlpA_kernel(
    const unsigned* __restrict__ enodes, const unsigned short* __restrict__ wp,
    const unsigned char* __restrict__ pb, const unsigned char* __restrict__ qb,
    const float* __restrict__ b2, const float* __restrict__ b3,
    float* __restrict__ out)
{
    __shared__ __align__(16) unsigned char smem[4 * 4608];

    const int tid  = threadIdx.x;
    const int lane = tid & 63;
    const int w    = tid >> 6;
    const int quad = lane >> 4;
    const int ln   = lane & 15;
    unsigned short* wbuf = (unsigned short*)(smem + w * 4608);  // L2: 32x72 u16 ; T: 64x36 u16 (bf16)
    const ushort8v* wpv = (const ushort8v*)wp;

    const int g = blockIdx.x * 4 + w;       // tile id, 25000 total
    const int ebase = g * 32;
    unsigned e0 = enodes[ebase + ln];
    unsigned e1 = enodes[ebase + 16 + ln];
    const int r0 = (int)(e0 & 0xFFFFu), cn0 = (int)(e0 >> 16);
    const int r1 = (int)(e1 & 0xFFFFu), cn1 = (int)(e1 >> 16);

    // ---- "layer 1": gather P[row] + Q[col] (both fp8, compact) -> h1 B-frags ----
    ushort8v H0[4], H1[4];
#pragma unroll
    for (int kc = 0; kc < 4; kc++){
        const int o = kc * 32 + quad * 8;
        uint2 p0 = *(const uint2*)(pb + (long)r0 * 128 + o);
        uint2 q0 = *(const uint2*)(qb + (long)cn0 * 128 + o);
        uint2 p1 = *(const uint2*)(pb + (long)r1 * 128 + o);
        uint2 q1 = *(const uint2*)(qb + (long)cn1 * 128 + o);
        H0[kc] = combine_relu_fp8(p0, q0);
        H1[kc] = combine_relu_fp8(p1, q1);
    }

    // ---- layer 2 (sets 8..15), two half-passes of 64 och each ----
    ushort8v G0[4], G1[4];
#pragma unroll
    for (int hv = 0; hv < 2; hv++){
#pragma unroll
        for (int q2 = 0; q2 < 4; q2++){
            int nt = hv * 4 + q2;
            floatx4 bini = *(const floatx4*)(b2 + nt * 16 + quad * 4);
            floatx4 a0 = bini, a1 = bini;
#pragma unroll
            for (int kc = 0; kc < 4; kc++){
                ushort8v Af = wpv[2048 + (nt * 4 + kc) * 64 + lane];
                a0 = mfma16(Af, H0[kc], a0);
                a1 = mfma16(Af, H1[kc], a1);
            }
            uint2 p0, p1;
            p0.x = pack2bf(fmaxf(a0[0], 0.f), fmaxf(a0[1], 0.f));
            p0.y = pack2bf(fmaxf(a0[2], 0.f), fmaxf(a0[3], 0.f));
            p1.x = pack2bf(fmaxf(a1[0], 0.f), fmaxf(a1[1], 0.f));
            p1.y = pack2bf(fmaxf(a1[2], 0.f), fmaxf(a1[3], 0.f));
            int col = q2 * 16 + quad * 4;
            *(uint2*)(wbuf + ln * 72 + col)        = p0;
            *(uint2*)(wbuf + (16 + ln) * 72 + col) = p1;
        }
#pragma unroll
        for (int c = 0; c < 2; c++){
            G0[hv * 2 + c] = *(const ushort8v*)(wbuf + ln * 72 + c * 32 + quad * 8);
            G1[hv * 2 + c] = *(const ushort8v*)(wbuf + (16 + ln) * 72 + c * 32 + quad * 8);
        }
    }

    // ---- layer 3 (sets 16..19) -> T bf16 [och 64][edge 32], LD=36 u16 ----
#pragma unroll
    for (int nt = 0; nt < 4; nt++){
        floatx4 bini = *(const floatx4*)(b3 + nt * 16 + quad * 4);
        floatx4 a0 = bini, a1 = bini;
#pragma unroll
        for (int kc = 0; kc < 4; kc++){
            ushort8v Af = wpv[4096 + (nt * 4 + kc) * 64 + lane];
            a0 = mfma16(Af, G0[kc], a0);
            a1 = mfma16(Af, G1[kc], a1);
        }
        int och = nt * 16 + quad * 4;
#pragma unroll
        for (int r = 0; r < 4; r++){
            wbuf[(och + r) * 36 + ln]      = f2bf(a0[r]);
            wbuf[(och + r) * 36 + 16 + ln] = f2bf(a1[r]);
        }
    }

    // ---- epilogue: all 64 lanes, lane = channel, run-reduce over 32 sorted edges ----
    float v[32];
#pragma unroll
    for (int t = 0; t < 8; t++){
        uint2 uu = *(const uint2*)(wbuf + lane * 36 + t * 4);   // byte addr lane*72: 8B-aligned
        v[t * 4 + 0] = __uint_as_float(uu.x << 16);
        v[t * 4 + 1] = __uint_as_float(uu.x & 0xFFFF0000u);
        v[t * 4 + 2] = __uint_as_float(uu.y << 16);
        v[t * 4 + 3] = __uint_as_float(uu.y & 0xFFFF0000u);
    }
    int cur = __builtin_amdgcn_readlane(cn0, 0);
    float s = v[0], mx = v[0], mn = v[0];
#pragma unroll
    for (int j = 1; j < 32; j++){
        int nj = (j < 16) ? __builtin_amdgcn_readlane(cn0, j)
                          : __builtin_amdgcn_readlane(cn1, j - 16);
        if (nj != cur){
            flush_run(out, cur, s, mx, mn, lane);
            cur = nj; s = v[j]; mx = v[j]; mn = v[j];
        } else {
            s += v[j]; mx = fmaxf(mx, v[j]); mn = fminf(mn, v[j]);
        }
    }
    flush_run(out, cur, s, mx, mn, lane);
}

// ---------------- edge MLP variant B: round-1 proven kernel (verbatim) ----------------
__global__ __launch_bounds__(256, 4) void edge_mlpB_kernel(
    const unsigned short* __restrict__ xbf, const int2* __restrict__ enodes,
    const unsigned short* __restrict__ wp,
    const float* __restrict__ b1, const float* __restrict__ b2, const float* __restrict__ b3,
    float* __restrict__ out)
{
    __shared__ __align__(16) unsigned char smem[4 * 8704];

    const int tid  = threadIdx.x;
    const int lane = tid & 63;
    const int w    = tid >> 6;
    const int quad = lane >> 4;
    const int ln   = lane & 15;
    unsigned short* wbuf = (unsigned short*)(smem + w * 8704);  // 32 rows x 136 u16
    float* Tf = (float*)wbuf;                                    // 64 rows x 33 f32
    const ushort8v* wpv = (const ushort8v*)wp;

    const int g = blockIdx.x * 4 + w;       // tile id, 25000 total
    const int ebase = g * 32;
    int2 ed0 = enodes[ebase + ln];
    int2 ed1 = enodes[ebase + 16 + ln];

    ushort8v Wb[3][4];
#define LDW(slot, idx) { _Pragma("unroll") for (int _k = 0; _k < 4; _k++) \
        Wb[slot][_k] = wpv[(idx) * 256 + _k * 64 + lane]; }

    LDW(0, 0)
    LDW(1, 1)

    const ushort8v* r0 = (const ushort8v*)(xbf + (long)ed0.x * 64);
    const ushort8v* c0 = (const ushort8v*)(xbf + (long)ed0.y * 64);
    const ushort8v* r1 = (const ushort8v*)(xbf + (long)ed1.x * 64);
    const ushort8v* c1 = (const ushort8v*)(xbf + (long)ed1.y * 64);
    ushort8v B0[4] = { r0[quad], r0[4 + quad], c0[quad], c0[4 + quad] };
    ushort8v B1[4] = { r1[quad], r1[4 + quad], c1[quad], c1[4 + quad] };

#pragma unroll
    for (int nt = 0; nt < 8; nt++){
        LDW((nt + 2) % 3, nt + 2)
        floatx4 bini = *(const floatx4*)(b1 + nt * 16 + quad * 4);
        floatx4 a0 = bini, a1 = bini;
#pragma unroll
        for (int kc = 0; kc < 4; kc++){
            a0 = mfma16(Wb[nt % 3][kc], B0[kc], a0);
            a1 = mfma16(Wb[nt % 3][kc], B1[kc], a1);
        }
        uint2 p0, p1;
        p0.x = pack2bf(fmaxf(a0[0], 0.f), fmaxf(a0[1], 0.f));
        p0.y = pack2bf(fmaxf(a0[2], 0.f), fmaxf(a0[3], 0.f));
        p1.x = pack2bf(fmaxf(a1[0], 0.f), fmaxf(a1[1], 0.f));
        p1.y = pack2bf(fmaxf(a1[2], 0.f), fmaxf(a1[3], 0.f));
        int col = nt * 16 + quad * 4;
        *(uint2*)(wbuf + ln * 136 + col)        = p0;
        *(uint2*)(wbuf + (16 + ln) * 136 + col) = p1;
    }

    ushort8v H0[4], H1[4];
#pragma unroll
    for (int kc = 0; kc < 4; kc++){
        H0[kc] = *(const ushort8v*)(wbuf + ln * 136 + kc * 32 + quad * 8);
        H1[kc] = *(const ushort8v*)(wbuf + (16 + ln) * 136 + kc * 32 + quad * 8);
    }
#pragma unroll
    for (int nt = 0; nt < 8; nt++){
        LDW((8 + nt + 2) % 3, 8 + nt + 2)
        floatx4 bini = *(const floatx4*)(b2 + nt * 16 + quad * 4);
        floatx4 a0 = bini, a1 = bini;
#pragma unroll
        for (int kc = 0; kc < 4; kc++){
            a0 = mfma16(Wb[(8 + nt) % 3][kc], H0[kc], a0);
            a1 = mfma16(Wb[(8 + nt) % 3][kc], H1[kc], a1);
        }
        uint2 p0, p1;
        p0.x = pack2bf(fmaxf(a0[0], 0.f), fmaxf(a0[1], 0.f));
        p0.y = pack2bf(fmaxf(a0[2], 0.f), fmaxf(a0[3], 0.f));
        p1.x = pack2bf(fmaxf(a1[0], 0.f), fmaxf(a1[1], 0.f));
        p1.y = pack2bf(fmaxf(a1[2], 0.f), fmaxf(a1[3], 0.f));
        int col = nt * 16 + quad * 4;
        *(uint2*)(wbuf + ln * 136 + col)        = p0;
        *(uint2*)(wbuf + (16 + ln) * 136 + col) = p1;
    }

    ushort8v G0[4], G1[4];
#pragma unroll
    for (int kc = 0; kc < 4; kc++){
        G0[kc] = *(const ushort8v*)(wbuf + ln * 136 + kc * 32 + quad * 8);
        G1[kc] = *(const ushort8v*)(wbuf + (16 + ln) * 136 + kc * 32 + quad * 8);
    }
#pragma unroll
    for (int nt = 0; nt < 4; nt++){
        if (nt < 2) LDW((16 + nt + 2) % 3, 16 + nt + 2)
        floatx4 bini = *(const floatx4*)(b3 + nt * 16 + quad * 4);
        floatx4 a0 = bini, a1 = bini;
#pragma unroll
        for (int kc = 0; kc < 4; kc++){
            a0 = mfma16(Wb[(16 + nt) % 3][kc], G0[kc], a0);
            a1 = mfma16(Wb[(16 + nt) % 3][kc], G1[kc], a1);
        }
        int och = nt * 16 + quad * 4;
#pragma unroll
        for (int r = 0; r < 4; r++){
            Tf[(och + r) * 33 + ln]      = a0[r];
            Tf[(och + r) * 33 + 16 + ln] = a1[r];
        }
    }

    float v[32];
#pragma unroll
    for (int j = 0; j < 32; j++) v[j] = Tf[lane * 33 + j];
    int cn0 = ed0.y, cn1 = ed1.y;
    int cur = __builtin_amdgcn_readlane(cn0, 0);
    float s = v[0], mx = v[0], mn = v[0];
#pragma unroll
    for (int j = 1; j < 32; j++){
        int nj = (j < 16) ? __builtin_amdgcn_readlane(cn0, j)
                          : __builtin_amdgcn_readlane(cn1, j - 16);
        if (nj != cur){
            flush_run(out, cur, s, mx, mn, lane);
            cur = nj; s = v[j]; mx = v[j]; mn = v[j];
        } else {
            s += v[j]; mx = fmaxf(mx, v[j]); mn = fminf(mn, v[j]);
        }
    }
    flush_run(out, cur, s, mx, mn, lane);
#undef LDW
}

// ---------------- finalize ----------------
__global__ void finalize_kernel(const float* __restrict__ x, const float* __restrict__ u,
                                const int* __restrict__ batch, const int* __restrict__ cnt,
                                float* __restrict__ out)
{
    long i = (long)blockIdx.x * blockDim.x + threadIdx.x;
    if (i >= (long)NN * 72) return;
    int ndx = (int)(i / 72);
    int q   = (int)(i % 72);
    float4 res;
    if (q < 16) {
        res = ((const float4*)(x + (long)ndx * 64))[q];
    } else if (q < 32) {
        float4 sv = ((const float4*)out)[i];
        int k = cnt[ndx];
        float inv = 1.f / (float)(k > 0 ? k : 1);
        res.x = sv.x * inv; res.y = sv.y * inv; res.z = sv.z * inv; res.w = sv.w * inv;
    } else if (q < 64) {
        uint4 e = ((const uint4*)out)[i];
        bool ne = cnt[ndx] > 0;
        res.x = ne ? decf(e.x) : 0.f; res.y = ne ? decf(e.y) : 0.f;
        res.z = ne ? decf(e.z) : 0.f; res.w = ne ? decf(e.w) : 0.f;
    } else {
        res = ((const float4*)(u + (long)batch[ndx] * 32))[q - 64];
    }
    ((float4*)out)[i] = res;
}

extern "C" void kernel_launch(void* const* d_in, const int* in_sizes, int n_in,
                              void* d_out, int out_size, void* d_ws, size_t ws_size,
                              hipStream_t stream)
{
    const float* x     = (const float*)d_in[0];
    const int*   ei    = (const int*)d_in[1];
    // d_in[2] = edge_attr (unused)
    const float* u     = (const float*)d_in[3];
    const int*   batch = (const int*)d_in[4];
    const float* W1    = (const float*)d_in[5];
    const float* b1    = (const float*)d_in[6];
    const float* W2    = (const float*)d_in[7];
    const float* b2    = (const float*)d_in[8];
    const float* W3    = (const float*)d_in[9];
    const float* b3    = (const float*)d_in[10];
    float* out = (float*)d_out;
    unsigned char* ws = (unsigned char*)d_ws;

    // common ws prefix
    unsigned short* wp    = (unsigned short*)ws;              //    81,920 B
    int*            cnt   = (int*)(ws + 81920);               //   200,000 B
    int*            off   = (int*)(ws + 281920);              //   200,000 B
    int*            bsum  = (int*)(ws + 481920);              //     1,024 B
    int*            bbase = (int*)(ws + 482944);              //     1,024 B

    const bool bigA = ws_size >= (size_t)16483968;

    hipMemsetAsync(cnt, 0, 200000, stream);
    if (bigA) {
        // layout A: enodes(u32 packed) 3.2MB | P fp8 6.4MB | Q fp8 6.4MB  -> 16,483,968 B
        unsigned*      enodes = (unsigned*)(ws + 483968);
        unsigned char* pb     = (unsigned char*)(ws + 3683968);
        unsigned char* qb     = (unsigned char*)(ws + 10083968);
        setup_kernel<0><<<(INIT_N + PK_N + E_EDGES + 255) / 256, 256, 0, stream>>>(
            x, ei, W1, W2, W3, wp, nullptr, cnt, out);
        pq_kernel<<<PQ_BLOCKS, 256, 0, stream>>>(x, wp, b1, pb, qb);
        scanA_kernel<<<256, 256, 0, stream>>>(cnt, off, bsum);
        scanB_kernel<<<1, 256, 0, stream>>>(bsum, bbase);
        scatterA_kernel<<<(E_EDGES + 255) / 256, 256, 0, stream>>>(ei, off, bbase, enodes);
        edge_mlpA_kernel<<<6250, 256, 0, stream>>>(enodes, wp, pb, qb, b2, b3, out);
    } else {
        // layout B (proven): enodes(int2) 6.4MB | xbf 6.4MB -> 13,283,968 B
        int2*           enodes = (int2*)(ws + 483968);
        unsigned short* xbf    = (unsigned short*)(ws + 6883968);
        setup_kernel<1><<<(INIT_N + XBF_N + PK_N + E_EDGES + 255) / 256, 256, 0, stream>>>(
            x, ei, W1, W2, W3, wp, xbf, cnt, out);
        scanA_kernel<<<256, 256, 0, stream>>>(cnt, off, bsum);
        scanB_kernel<<<1, 256, 0, stream>>>(bsum, bbase);
        scatterB_kernel<<<(E_EDGES + 255) / 256, 256, 0, stream>>>(ei, off, bbase, enodes);
        edge_mlpB_kernel<<<6250, 256, 0, stream>>>(xbf, enodes, wp, b1, b2, b3, out);
    }
    finalize_kernel<<<(int)(((long)NN * 72 + 255) / 256), 256, 0, stream>>>(x, u, batch, cnt, out);
}